// Round 1
// baseline (191.842 us; speedup 1.0000x reference)
//
#include <hip/hip_runtime.h>
#include <math.h>

// DirectVolumeRenderer: 128x128 image, 256 samples/ray, two 128^3 f32 volumes.
// Kernel 1: one wave (64 lanes) per pixel, 4 samples per lane.
//   - per-lane: local transmittance product lp and local weighted feature accl
//   - cross-lane exclusive prefix product (shfl_up scan) gives each lane its
//     incoming transmittance; acc = accl * excl; wave-sum -> gray value.
// Kernel 2: single block computes mean/std(ddof=1)/min/max (double accum) and
//   applies out = ((g-gmin)/s + 1e-8) / ((gmax-gmin)/s + 1e-8).

#define FOCAL 1.7320508f

__global__ __launch_bounds__(256) void render_kernel(
    const float* __restrict__ img, const float* __restrict__ opa,
    const float* __restrict__ Rm, const float* __restrict__ Tv,
    float* __restrict__ g)
{
  const int lane = threadIdx.x & 63;
  const int wave = threadIdx.x >> 6;
  const int pix  = (blockIdx.x << 2) + wave;   // 4096 blocks * 4 waves = 16384
  const int h = pix >> 7;
  const int w = pix & 127;

  // camera (row-vector convention): origin = -T @ R^T ; dir_world = dir_cam @ R^T
  const float R00=Rm[0], R01=Rm[1], R02=Rm[2];
  const float R10=Rm[3], R11=Rm[4], R12=Rm[5];
  const float R20=Rm[6], R21=Rm[7], R22=Rm[8];
  const float T0=Tv[0], T1=Tv[1], T2=Tv[2];

  const float ox = -(T0*R00 + T1*R01 + T2*R02);
  const float oy = -(T0*R10 + T1*R11 + T2*R12);
  const float oz = -(T0*R20 + T1*R21 + T2*R22);

  const float gx = 1.0f - (2.0f/127.0f) * (float)w;   // xs = linspace(1,-1,128)
  const float gy = 1.0f - (2.0f/127.0f) * (float)h;
  const float dcx = gx * (1.0f/FOCAL);
  const float dcy = gy * (1.0f/FOCAL);
  const float dwx = dcx*R00 + dcy*R01 + R02;
  const float dwy = dcx*R10 + dcy*R11 + R12;
  const float dwz = dcx*R20 + dcy*R21 + R22;

  // half_extent = (3/128) * 127 / 2  (same for x,y,z since D=H=W=128)
  const float inv_he = 1.0f / ((3.0f/128.0f) * 127.0f * 0.5f);

  float lp   = 1.0f;   // local transmittance product over this lane's samples
  float accl = 0.0f;   // local weighted feature sum (relative to lane start)

  #pragma unroll
  for (int j = 0; j < 4; ++j) {
    const int p = (lane << 2) + j;                       // sample index 0..255
    const float depth = 2.0f + (4.0f/255.0f) * (float)p; // linspace(2,6,256)
    const float px = (ox + depth*dwx) * inv_he;
    const float py = (oy + depth*dwy) * inv_he;
    const float pz = (oz + depth*dwz) * inv_he;

    // grid_sample align_corners=True, zero padding
    const float x = (px + 1.0f) * (0.5f * 127.0f);
    const float y = (py + 1.0f) * (0.5f * 127.0f);
    const float z = (pz + 1.0f) * (0.5f * 127.0f);
    const float x0f = floorf(x), y0f = floorf(y), z0f = floorf(z);
    const float wx = x - x0f, wy = y - y0f, wz = z - z0f;
    const int x0 = (int)x0f, y0 = (int)y0f, z0 = (int)z0f;

    float feat = 0.0f, dens = 0.0f;
    if (x0 >= -1 && x0 <= 127 && y0 >= -1 && y0 <= 127 &&
        z0 >= -1 && z0 <= 127) {
      #pragma unroll
      for (int c = 0; c < 8; ++c) {
        const int dx = c & 1, dy = (c >> 1) & 1, dz = (c >> 2) & 1;
        const int xi = x0 + dx, yi = y0 + dy, zi = z0 + dz;
        if ((unsigned)xi < 128u && (unsigned)yi < 128u && (unsigned)zi < 128u) {
          const float wgt = (dx ? wx : 1.0f - wx)
                          * (dy ? wy : 1.0f - wy)
                          * (dz ? wz : 1.0f - wz);
          const int idx = (zi << 14) + (yi << 7) + xi;
          feat += wgt * img[idx];
          dens += wgt * opa[idx];
        }
      }
    }
    dens *= 0.1f;                 // SCALING (linear -> can apply post-interp)
    accl += feat * dens * lp;     // weight_p = dens_p * (incoming transmittance)
    lp   *= (1.0f - dens);        // (1 + 1e-10) - dens == 1 - dens in f32
  }

  // exclusive cross-lane prefix product of transmittance
  float scan = lp;
  #pragma unroll
  for (int off = 1; off < 64; off <<= 1) {
    float o = __shfl_up(scan, off, 64);
    if (lane >= off) scan *= o;
  }
  float excl = __shfl_up(scan, 1, 64);
  if (lane == 0) excl = 1.0f;

  float acc = accl * excl;
  #pragma unroll
  for (int off = 32; off >= 1; off >>= 1)
    acc += __shfl_xor(acc, off, 64);

  if (lane == 0) g[w * 128 + h] = acc;   // transposed output layout [W,H]
}

__global__ __launch_bounds__(256) void finalize_kernel(
    const float* __restrict__ g, float* __restrict__ out)
{
  __shared__ double s_sum[256];
  __shared__ double s_sq[256];
  __shared__ float  s_mn[256];
  __shared__ float  s_mx[256];
  const int tid = threadIdx.x;

  double sum = 0.0, sq = 0.0;
  float mn = 3.402823466e38f, mx = -3.402823466e38f;
  for (int i = tid; i < 16384; i += 256) {
    const float v = g[i];
    sum += (double)v;
    sq  += (double)v * (double)v;
    mn = fminf(mn, v);
    mx = fmaxf(mx, v);
  }
  s_sum[tid] = sum; s_sq[tid] = sq; s_mn[tid] = mn; s_mx[tid] = mx;
  __syncthreads();
  for (int s = 128; s > 0; s >>= 1) {
    if (tid < s) {
      s_sum[tid] += s_sum[tid + s];
      s_sq[tid]  += s_sq[tid + s];
      s_mn[tid]  = fminf(s_mn[tid], s_mn[tid + s]);
      s_mx[tid]  = fmaxf(s_mx[tid], s_mx[tid + s]);
    }
    __syncthreads();
  }

  __shared__ float p_mn, p_invs, p_scale;
  if (tid == 0) {
    const double mean = s_sum[0] / 16384.0;
    double var = (s_sq[0] - 16384.0 * mean * mean) / 16383.0;
    if (var < 0.0) var = 0.0;
    const float sdev = (float)sqrt(var) + 1e-8f;    // std(ddof=1) + 1e-8
    p_mn    = s_mn[0];
    p_invs  = 1.0f / sdev;
    p_scale = 1.0f / ((s_mx[0] - s_mn[0]) / sdev + 1e-8f);
  }
  __syncthreads();

  const float mnv = p_mn, invs = p_invs, sc = p_scale;
  for (int i = tid; i < 16384; i += 256) {
    out[i] = ((g[i] - mnv) * invs + 1e-8f) * sc;
  }
}

extern "C" void kernel_launch(void* const* d_in, const int* in_sizes, int n_in,
                              void* d_out, int out_size, void* d_ws, size_t ws_size,
                              hipStream_t stream) {
  const float* img = (const float*)d_in[0];   // image3d [1,1,128,128,128]
  const float* opa = (const float*)d_in[1];   // opacity [1,1,128,128,128]
  const float* Rm  = (const float*)d_in[2];   // R [1,3,3]
  const float* Tv  = (const float*)d_in[3];   // T [1,3]
  float* out = (float*)d_out;                 // [1,1,128,128] f32
  float* g   = (float*)d_ws;                  // 16384 floats of scratch

  render_kernel<<<4096, 256, 0, stream>>>(img, opa, Rm, Tv, g);
  finalize_kernel<<<1, 256, 0, stream>>>(g, out);
}

// Round 2
// 98.671 us; speedup vs baseline: 1.9443x; 1.9443x over previous
//
#include <hip/hip_runtime.h>
#include <math.h>

// DirectVolumeRenderer: 128x128 image, 256 samples/ray, two 128^3 f32 volumes.
//
// Pass 1 (render): lane = pixel-x (coalesced volume gathers: adjacent lanes are
//   ~1-2 voxels apart along the contiguous W axis -> ~4-10 cache lines per
//   gather instruction instead of 64). Wave = 64 consecutive x-pixels of one
//   row, processing one 16-sample ray segment. Emits per-segment
//   (partial_weighted_feature, transmittance) -- the EA recurrence is
//   associative, so segments compose.
// Pass 2 (combine): per-pixel scan over segments -> gray value + per-block
//   stats partials (sum/sumsq/min/max, double accum).
// Pass 3 (finalize): each of 64 blocks redundantly reduces the 64 stats
//   partials (cheap) and normalizes its 256 pixels with transposed write.

#define FOCAL 1.7320508f

__global__ __launch_bounds__(256) void render_kernel(
    const float* __restrict__ img, const float* __restrict__ opa,
    const float* __restrict__ Rm, const float* __restrict__ Tv,
    float2* __restrict__ partial, int nseg_shift)
{
  const int lane   = threadIdx.x & 63;
  const int waveid = threadIdx.x >> 6;
  const int wg     = (blockIdx.x << 2) + waveid;
  const int nseg   = 1 << nseg_shift;
  const int seg    = wg & (nseg - 1);      // block = same pixel group, 4 segs
  const int pg     = wg >> nseg_shift;     // 0..255 pixel groups
  const int h      = pg >> 1;
  const int w      = ((pg & 1) << 6) | lane;

  // camera (row-vector convention): origin = -T @ R^T ; dir_world = dir_cam @ R^T
  const float R00=Rm[0], R01=Rm[1], R02=Rm[2];
  const float R10=Rm[3], R11=Rm[4], R12=Rm[5];
  const float R20=Rm[6], R21=Rm[7], R22=Rm[8];
  const float T0=Tv[0], T1=Tv[1], T2=Tv[2];

  const float ox = -(T0*R00 + T1*R01 + T2*R02);
  const float oy = -(T0*R10 + T1*R11 + T2*R12);
  const float oz = -(T0*R20 + T1*R21 + T2*R22);

  const float gx = 1.0f - (2.0f/127.0f) * (float)w;   // xs = linspace(1,-1,128)
  const float gy = 1.0f - (2.0f/127.0f) * (float)h;
  const float dcx = gx * (1.0f/FOCAL);
  const float dcy = gy * (1.0f/FOCAL);
  const float dwx = dcx*R00 + dcy*R01 + R02;
  const float dwy = dcx*R10 + dcy*R11 + R12;
  const float dwz = dcx*R20 + dcy*R21 + R22;

  // half_extent = (3/128)*127/2 = 1.48828125 exactly; voxel coord = (p/he+1)*63.5
  const float s_he = (1.0f/1.48828125f) * 63.5f;
  const float ax = dwx * s_he, bx = ox * s_he + 63.5f;
  const float ay = dwy * s_he, by = oy * s_he + 63.5f;
  const float az = dwz * s_he, bz = oz * s_he + 63.5f;

  const int spseg = 256 >> nseg_shift;
  const int p0 = seg * spseg;

  float lp = 1.0f;     // transmittance over this segment
  float accl = 0.0f;   // weighted feature sum (relative to segment start)

  for (int j = 0; j < spseg; ++j) {
    const float depth = 2.0f + (4.0f/255.0f) * (float)(p0 + j);  // linspace(2,6,256)
    const float x = bx + depth * ax;
    const float y = by + depth * ay;
    const float z = bz + depth * az;
    const float x0f = floorf(x), y0f = floorf(y), z0f = floorf(z);
    const float wx = x - x0f, wy = y - y0f, wz = z - z0f;
    const int x0 = (int)x0f, y0 = (int)y0f, z0 = (int)z0f;

    float feat = 0.0f, dens = 0.0f;
    if (x0 >= -1 && x0 <= 127 && y0 >= -1 && y0 <= 127 &&
        z0 >= -1 && z0 <= 127) {
      // per-axis validity folded into the weights; indices clamped in-bounds
      const float fx0 = (x0 >= 0)   ? (1.0f - wx) : 0.0f;
      const float fx1 = (x0 <= 126) ? wx          : 0.0f;
      const float fy0 = (y0 >= 0)   ? (1.0f - wy) : 0.0f;
      const float fy1 = (y0 <= 126) ? wy          : 0.0f;
      const float fz0 = (z0 >= 0)   ? (1.0f - wz) : 0.0f;
      const float fz1 = (z0 <= 126) ? wz          : 0.0f;
      const int ix0 = (x0 >= 0)   ? x0     : 0;
      const int ix1 = (x0 <= 126) ? x0 + 1 : 127;
      const int iy0 = ((y0 >= 0)   ? y0     : 0)   << 7;
      const int iy1 = ((y0 <= 126) ? y0 + 1 : 127) << 7;
      const int iz0 = ((z0 >= 0)   ? z0     : 0)   << 14;
      const int iz1 = ((z0 <= 126) ? z0 + 1 : 127) << 14;

      const int b00 = iz0 + iy0, b01 = iz0 + iy1;
      const int b10 = iz1 + iy0, b11 = iz1 + iy1;
      const float w00 = fz0*fy0, w01 = fz0*fy1, w10 = fz1*fy0, w11 = fz1*fy1;

      feat = w00*(fx0*img[b00+ix0] + fx1*img[b00+ix1])
           + w01*(fx0*img[b01+ix0] + fx1*img[b01+ix1])
           + w10*(fx0*img[b10+ix0] + fx1*img[b10+ix1])
           + w11*(fx0*img[b11+ix0] + fx1*img[b11+ix1]);
      dens = w00*(fx0*opa[b00+ix0] + fx1*opa[b00+ix1])
           + w01*(fx0*opa[b01+ix0] + fx1*opa[b01+ix1])
           + w10*(fx0*opa[b10+ix0] + fx1*opa[b10+ix1])
           + w11*(fx0*opa[b11+ix0] + fx1*opa[b11+ix1]);
    }
    const float d = dens * 0.1f;       // SCALING
    accl += feat * d * lp;             // weight = dens * incoming transmittance
    lp   *= (1.0f - d);                // (1+1e-10)-d == 1-d in f32
  }

  partial[(seg << 14) + (h << 7) + w] = make_float2(accl, lp);
}

__global__ __launch_bounds__(256) void combine_kernel(
    const float2* __restrict__ partial, float* __restrict__ g,
    double* __restrict__ bstats, int nseg)
{
  const int tid = threadIdx.x;
  const int pid = (blockIdx.x << 8) + tid;   // pid = h*128 + w

  float T = 1.0f, acc = 0.0f;
  for (int s = 0; s < nseg; ++s) {
    const float2 v = partial[(s << 14) + pid];
    acc += v.x * T;
    T *= v.y;
  }
  g[pid] = acc;

  // per-block stats partials
  double sum = (double)acc;
  double sq  = (double)acc * (double)acc;
  float mn = acc, mx = acc;
  #pragma unroll
  for (int off = 32; off >= 1; off >>= 1) {
    sum += __shfl_xor(sum, off, 64);
    sq  += __shfl_xor(sq,  off, 64);
    mn = fminf(mn, __shfl_xor(mn, off, 64));
    mx = fmaxf(mx, __shfl_xor(mx, off, 64));
  }
  __shared__ double s_sum[4], s_sq[4];
  __shared__ float  s_mn[4], s_mx[4];
  const int wv = tid >> 6;
  if ((tid & 63) == 0) { s_sum[wv]=sum; s_sq[wv]=sq; s_mn[wv]=mn; s_mx[wv]=mx; }
  __syncthreads();
  if (tid == 0) {
    double S = 0.0, Q = 0.0;
    float MN = s_mn[0], MX = s_mx[0];
    #pragma unroll
    for (int i = 0; i < 4; ++i) {
      S += s_sum[i]; Q += s_sq[i];
      MN = fminf(MN, s_mn[i]); MX = fmaxf(MX, s_mx[i]);
    }
    bstats[(blockIdx.x << 2) + 0] = S;
    bstats[(blockIdx.x << 2) + 1] = Q;
    bstats[(blockIdx.x << 2) + 2] = (double)MN;
    bstats[(blockIdx.x << 2) + 3] = (double)MX;
  }
}

__global__ __launch_bounds__(256) void finalize_kernel(
    const float* __restrict__ g, const double* __restrict__ bstats,
    float* __restrict__ out)
{
  __shared__ float sh[3];
  const int tid = threadIdx.x;
  if (tid < 64) {
    double S  = bstats[(tid << 2) + 0];
    double Q  = bstats[(tid << 2) + 1];
    double MN = bstats[(tid << 2) + 2];
    double MX = bstats[(tid << 2) + 3];
    #pragma unroll
    for (int off = 32; off >= 1; off >>= 1) {
      S += __shfl_xor(S, off, 64);
      Q += __shfl_xor(Q, off, 64);
      MN = fmin(MN, __shfl_xor(MN, off, 64));
      MX = fmax(MX, __shfl_xor(MX, off, 64));
    }
    if (tid == 0) {
      const double mean = S / 16384.0;
      double var = (Q - 16384.0 * mean * mean) / 16383.0;
      if (var < 0.0) var = 0.0;
      const float sdev = (float)sqrt(var) + 1e-8f;   // std(ddof=1) + 1e-8
      const float mnf = (float)MN, mxf = (float)MX;
      sh[0] = mnf;
      sh[1] = 1.0f / sdev;
      sh[2] = 1.0f / ((mxf - mnf) / sdev + 1e-8f);
    }
  }
  __syncthreads();
  const float mnv = sh[0], invs = sh[1], sc = sh[2];
  const int pid = (blockIdx.x << 8) + tid;    // pid = h*128 + w
  const float v = g[pid];
  const int hh = pid >> 7, ww = pid & 127;
  out[(ww << 7) + hh] = ((v - mnv) * invs + 1e-8f) * sc;   // transposed write
}

extern "C" void kernel_launch(void* const* d_in, const int* in_sizes, int n_in,
                              void* d_out, int out_size, void* d_ws, size_t ws_size,
                              hipStream_t stream) {
  const float* img = (const float*)d_in[0];   // image3d [1,1,128,128,128]
  const float* opa = (const float*)d_in[1];   // opacity [1,1,128,128,128]
  const float* Rm  = (const float*)d_in[2];   // R [1,3,3]
  const float* Tv  = (const float*)d_in[3];   // T [1,3]
  float* out = (float*)d_out;                 // [1,1,128,128] f32 (W,H layout)

  // pick segment count that fits ws: partials (1 MB<<shift) + g (64KB) + stats
  int shift = 4;
  while (shift > 0) {
    const size_t need = ((size_t)131072 << shift) + 65536 + 2048;
    if (need <= ws_size) break;
    --shift;
  }
  const int nseg = 1 << shift;

  char* wsb = (char*)d_ws;
  float2* partial = (float2*)wsb;
  float*  g       = (float*)(wsb + ((size_t)131072 << shift));
  double* bstats  = (double*)(wsb + ((size_t)131072 << shift) + 65536);

  render_kernel<<<64 * nseg, 256, 0, stream>>>(img, opa, Rm, Tv, partial, shift);
  combine_kernel<<<64, 256, 0, stream>>>(partial, g, bstats, nseg);
  finalize_kernel<<<64, 256, 0, stream>>>(g, bstats, out);
}